// Round 1
// baseline (242.626 us; speedup 1.0000x reference)
//
#include <hip/hip_runtime.h>
#include <math.h>

#define N_ATOMS 4096
#define SPECIES 100
#define FEA 64
#define M_NBR 12

constexpr float LN_EPS = 1e-5f;
constexpr float GAUSS_COEFF = -31.0078125f; // -0.5/(8/63)^2

__device__ __forceinline__ float sigmoidf(float x){ return 1.0f/(1.0f+expf(-x)); }
__device__ __forceinline__ float softplusf(float x){
    float ax = fabsf(x);
    float r = log1pf(expf(-ax));
    return x > 0.0f ? x + r : r;
}

// ---------------- embedding: softmax(species_logits) @ emb_w + emb_b ----------------
__global__ __launch_bounds__(256) void k_embed(const float* __restrict__ logits,
        const float* __restrict__ emb_w, const float* __restrict__ emb_b,
        float* __restrict__ atom0){
    __shared__ float sE[4][SPECIES];
    int tid = threadIdx.x;
    int grp = tid >> 6;      // wave id: one atom per wave
    int f = tid & 63;
    int a = blockIdx.x * 4 + grp;
    const float* lg = logits + (long)a * SPECIES;
    float l0 = lg[f];
    float l1 = (f + 64 < SPECIES) ? lg[f + 64] : -1e30f;
    float mx = fmaxf(l0, l1);
    #pragma unroll
    for (int off = 32; off; off >>= 1) mx = fmaxf(mx, __shfl_xor(mx, off));
    float e0 = expf(l0 - mx);
    float e1 = (f + 64 < SPECIES) ? expf(l1 - mx) : 0.0f;
    sE[grp][f] = e0;
    if (f + 64 < SPECIES) sE[grp][64 + f] = e1;
    float sm = e0 + e1;
    #pragma unroll
    for (int off = 32; off; off >>= 1) sm += __shfl_xor(sm, off);
    __syncthreads();
    float acc = 0.0f;
    for (int s = 0; s < SPECIES; ++s) acc += sE[grp][s] * emb_w[s * FEA + f];
    atom0[(long)a * FEA + f] = acc / sm + emb_b[f];
}

// ---------------- pairwise min-image distances + top-12 smallest ----------------
__global__ __launch_bounds__(256) void k_topk(const float* __restrict__ fracs,
        const float* __restrict__ lat, int* __restrict__ nbr_idx,
        float* __restrict__ nbr_dist){
    __shared__ float sD2[N_ATOMS];
    __shared__ float sWv[4];
    __shared__ int   sWi[4];
    int i = blockIdx.x, tid = threadIdx.x;
    float l00=lat[0],l01=lat[1],l02=lat[2];
    float l10=lat[3],l11=lat[4],l12=lat[5];
    float l20=lat[6],l21=lat[7],l22=lat[8];
    float fx = fracs[i*3+0], fy = fracs[i*3+1], fz = fracs[i*3+2];
    #pragma unroll
    for (int k = 0; k < 16; ++k){
        int j = tid + k * 256;
        float dx = fx - fracs[j*3+0];
        float dy = fy - fracs[j*3+1];
        float dz = fz - fracs[j*3+2];
        dx -= rintf(dx); dy -= rintf(dy); dz -= rintf(dz);
        float cx = dx*l00 + dy*l10 + dz*l20;
        float cy = dx*l01 + dy*l11 + dz*l21;
        float cz = dx*l02 + dy*l12 + dz*l22;
        float d2 = cx*cx + cy*cy + cz*cz;
        sD2[j] = (j == i) ? 3.4e38f : d2;
    }
    __syncthreads();
    for (int r = 0; r < M_NBR; ++r){
        float v = 3.4e38f; int id = N_ATOMS;
        #pragma unroll
        for (int k = 0; k < 16; ++k){
            int j = tid + k * 256;
            float x = sD2[j];
            if (x < v || (x == v && j < id)){ v = x; id = j; }
        }
        #pragma unroll
        for (int off = 32; off; off >>= 1){
            float ov = __shfl_down(v, off);
            int   oi = __shfl_down(id, off);
            if (ov < v || (ov == v && oi < id)){ v = ov; id = oi; }
        }
        if ((tid & 63) == 0){ sWv[tid >> 6] = v; sWi[tid >> 6] = id; }
        __syncthreads();
        if (tid == 0){
            float bv = sWv[0]; int bi = sWi[0];
            #pragma unroll
            for (int w = 1; w < 4; ++w){
                if (sWv[w] < bv || (sWv[w] == bv && sWi[w] < bi)){ bv = sWv[w]; bi = sWi[w]; }
            }
            nbr_idx[i * M_NBR + r]  = bi;
            nbr_dist[i * M_NBR + r] = sqrtf(bv);
            sD2[bi] = 3.4e38f;
        }
        __syncthreads();
    }
}

// ---------------- CGCNN conv layer ----------------
// selfF: [N,64] current atom features; nbrF: [N,64] ORIGINAL embedding (both layers)
// z[m][c] = LN( concat(self, nbr_m, gauss_m) @ w + b )[c];  c in [0,128)
// out[c<64] = softplus(self[c] + sum_m sigmoid(z[m][c]) * softplus(z[m][c+64]))
__global__ __launch_bounds__(128) void k_layer(const float* __restrict__ selfF,
        const float* __restrict__ nbrF, const int* __restrict__ nbr_idx,
        const float* __restrict__ nbr_dist, const float* __restrict__ w,
        const float* __restrict__ b, const float* __restrict__ g,
        const float* __restrict__ be, float* __restrict__ outF){
    __shared__ float sSelf[FEA];
    __shared__ float sT[M_NBR][128];   // [nbr fea 64 | gaussians 64]
    __shared__ float sZ[M_NBR][128];
    __shared__ int   sIdx[M_NBR];
    __shared__ float sDist[M_NBR];
    __shared__ float sRS[M_NBR][2], sRQ[M_NBR][2];
    int i = blockIdx.x, c = threadIdx.x;
    if (c < FEA) sSelf[c] = selfF[(long)i * FEA + c];
    if (c < M_NBR){ sIdx[c] = nbr_idx[i * M_NBR + c]; sDist[c] = nbr_dist[i * M_NBR + c]; }
    __syncthreads();
    for (int m = 0; m < M_NBR; ++m){
        if (c < 64){
            sT[m][c] = nbrF[(long)sIdx[m] * FEA + c];
        } else {
            int kk = c - 64;
            float off = 8.0f * (float)kk / 63.0f;
            float t = sDist[m] - off;
            sT[m][c] = expf(GAUSS_COEFF * t * t);
        }
    }
    __syncthreads();
    // rows 0..63 of w: self contribution (identical for every neighbor)
    float selfdot = 0.0f;
    for (int k = 0; k < 64; ++k) selfdot += sSelf[k] * w[k * 128 + c];
    float acc[M_NBR];
    float bc = b[c];
    #pragma unroll
    for (int m = 0; m < M_NBR; ++m) acc[m] = selfdot + bc;
    // rows 64..191: nbr fea + gaussians
    for (int k4 = 0; k4 < 32; ++k4){
        int k = 4 * k4;
        float w0 = w[(64 + k) * 128 + c];
        float w1 = w[(65 + k) * 128 + c];
        float w2 = w[(66 + k) * 128 + c];
        float w3 = w[(67 + k) * 128 + c];
        #pragma unroll
        for (int m = 0; m < M_NBR; ++m){
            float4 t = reinterpret_cast<const float4*>(sT[m])[k4];
            acc[m] = fmaf(t.x, w0, fmaf(t.y, w1, fmaf(t.z, w2, fmaf(t.w, w3, acc[m]))));
        }
    }
    // LayerNorm over the 128 channels (2 waves)
    int lane = c & 63, wid = c >> 6;
    #pragma unroll
    for (int m = 0; m < M_NBR; ++m){
        float s = acc[m], q = acc[m] * acc[m];
        #pragma unroll
        for (int off = 32; off; off >>= 1){ s += __shfl_down(s, off); q += __shfl_down(q, off); }
        if (lane == 0){ sRS[m][wid] = s; sRQ[m][wid] = q; }
    }
    __syncthreads();
    float gc = g[c], bec = be[c];
    #pragma unroll
    for (int m = 0; m < M_NBR; ++m){
        float mean = (sRS[m][0] + sRS[m][1]) * (1.0f / 128.0f);
        float var  = (sRQ[m][0] + sRQ[m][1]) * (1.0f / 128.0f) - mean * mean;
        float zn = (acc[m] - mean) * rsqrtf(var + LN_EPS) * gc + bec;
        sZ[m][c] = zn;
    }
    __syncthreads();
    if (c < 64){
        float nsum = 0.0f;
        #pragma unroll
        for (int m = 0; m < M_NBR; ++m){
            nsum += sigmoidf(sZ[m][c]) * softplusf(sZ[m][c + 64]);
        }
        outF[(long)i * FEA + c] = softplusf(sSelf[c] + nsum);
    }
}

// ---------------- pooling: deterministic two-stage tree ----------------
__global__ __launch_bounds__(256) void k_partial(const float* __restrict__ atom,
        const float* __restrict__ occ, float* __restrict__ partials){
    int b = blockIdx.x, tid = threadIdx.x;
    int f = tid & 63, sub = tid >> 6;
    __shared__ float sAcc[256];
    float acc = 0.0f;
    for (int it = 0; it < 16; ++it){
        int a = b * 64 + sub + it * 4;
        float p = sigmoidf(occ[a]);
        acc += atom[(long)a * FEA + f] * p;
    }
    sAcc[tid] = acc;
    __syncthreads();
    if (tid < 64){
        float s = sAcc[f] + sAcc[64 + f] + sAcc[128 + f] + sAcc[192 + f];
        partials[b * 65 + f] = s;
        float po = sigmoidf(occ[b * 64 + f]);
        #pragma unroll
        for (int off = 32; off; off >>= 1) po += __shfl_down(po, off);
        if (f == 0) partials[b * 65 + 64] = po;
    }
}

__global__ __launch_bounds__(64) void k_final(const float* __restrict__ partials,
        const float* __restrict__ fc_w, const float* __restrict__ fc_b,
        float* __restrict__ out){
    int f = threadIdx.x;
    float num = 0.0f;
    for (int p = 0; p < 64; ++p) num += partials[p * 65 + f];
    float occs = partials[f * 65 + 64];
    #pragma unroll
    for (int off = 32; off; off >>= 1) occs += __shfl_down(occs, off);
    occs = __shfl(occs, 0);
    float gf = num / (occs + 1e-6f);
    float v = gf * fc_w[f];
    #pragma unroll
    for (int off = 32; off; off >>= 1) v += __shfl_down(v, off);
    if (f == 0) out[0] = v + fc_b[0];
}

extern "C" void kernel_launch(void* const* d_in, const int* in_sizes, int n_in,
                              void* d_out, int out_size, void* d_ws, size_t ws_size,
                              hipStream_t stream) {
    const float* lat    = (const float*)d_in[0];
    const float* fracs  = (const float*)d_in[1];
    const float* slog   = (const float*)d_in[2];
    const float* occ    = (const float*)d_in[3];
    const float* emb_w  = (const float*)d_in[4];
    const float* emb_b  = (const float*)d_in[5];
    const float* w1     = (const float*)d_in[6];
    const float* b1     = (const float*)d_in[7];
    const float* g1     = (const float*)d_in[8];
    const float* be1    = (const float*)d_in[9];
    const float* w2     = (const float*)d_in[10];
    const float* b2     = (const float*)d_in[11];
    const float* g2     = (const float*)d_in[12];
    const float* be2    = (const float*)d_in[13];
    const float* fc_w   = (const float*)d_in[14];
    const float* fc_b   = (const float*)d_in[15];
    float* out = (float*)d_out;

    char* ws = (char*)d_ws;
    int*   nbr_idx  = (int*)ws;           ws += (size_t)N_ATOMS * M_NBR * 4;
    float* nbr_dist = (float*)ws;         ws += (size_t)N_ATOMS * M_NBR * 4;
    float* atom0    = (float*)ws;         ws += (size_t)N_ATOMS * FEA * 4;
    float* atom1    = (float*)ws;         ws += (size_t)N_ATOMS * FEA * 4;
    float* partials = (float*)ws;         ws += (size_t)64 * 65 * 4;

    k_embed  <<<N_ATOMS / 4, 256, 0, stream>>>(slog, emb_w, emb_b, atom0);
    k_topk   <<<N_ATOMS, 256, 0, stream>>>(fracs, lat, nbr_idx, nbr_dist);
    k_layer  <<<N_ATOMS, 128, 0, stream>>>(atom0, atom0, nbr_idx, nbr_dist, w1, b1, g1, be1, atom1);
    k_layer  <<<N_ATOMS, 128, 0, stream>>>(atom1, atom0, nbr_idx, nbr_dist, w2, b2, g2, be2, atom1);
    k_partial<<<64, 256, 0, stream>>>(atom1, occ, partials);
    k_final  <<<1, 64, 0, stream>>>(partials, fc_w, fc_b, out);
}

// Round 2
// 165.141 us; speedup vs baseline: 1.4692x; 1.4692x over previous
//
#include <hip/hip_runtime.h>
#include <math.h>

#define N_ATOMS 4096
#define SPECIES 100
#define FEA 64
#define M_NBR 12

typedef unsigned short u16;
typedef __attribute__((ext_vector_type(8))) short bf16x8;
typedef __attribute__((ext_vector_type(4))) float f32x4;

constexpr float LN_EPS = 1e-5f;
constexpr float GAUSS_COEFF = -31.0078125f; // -0.5/(8/63)^2

__device__ __forceinline__ float sigmoidf_(float x){ return 1.0f/(1.0f+__expf(-x)); }
__device__ __forceinline__ float softplusf_(float x){
    return fmaxf(x, 0.0f) + log1pf(__expf(-fabsf(x)));
}
// split f32 into bf16 hi + bf16 lo (round-to-nearest-even via bit trick)
__device__ __forceinline__ void split_bf16(float x, u16& h, u16& l){
    unsigned u = __float_as_uint(x);
    unsigned hr = (u + 0x7FFFu + ((u >> 16) & 1u)) >> 16;
    h = (u16)hr;
    float hf = __uint_as_float(hr << 16);
    float lo = x - hf;
    unsigned u2 = __float_as_uint(lo);
    l = (u16)((u2 + 0x7FFFu + ((u2 >> 16) & 1u)) >> 16);
}

// ---------------- weight prep: W[192][128] f32 -> W^T[128][192] bf16 hi/lo ----------------
__global__ __launch_bounds__(256) void k_prepw(const float* __restrict__ w1,
        const float* __restrict__ w2, u16* __restrict__ wt1h, u16* __restrict__ wt1l,
        u16* __restrict__ wt2h, u16* __restrict__ wt2l){
    int gid = blockIdx.x * 256 + threadIdx.x;      // 0..49151
    int layer = gid / 24576;
    int e = gid % 24576;
    int k = e >> 7, n = e & 127;
    const float* w = layer ? w2 : w1;
    float x = w[e];
    u16 h, l; split_bf16(x, h, l);
    u16* th = layer ? wt2h : wt1h;
    u16* tl = layer ? wt2l : wt1l;
    th[n * 192 + k] = h;
    tl[n * 192 + k] = l;
}

// ---------------- embedding: softmax(species_logits) @ emb_w + emb_b ----------------
__global__ __launch_bounds__(256) void k_embed(const float* __restrict__ logits,
        const float* __restrict__ emb_w, const float* __restrict__ emb_b,
        float* __restrict__ atom0, u16* __restrict__ a0h, u16* __restrict__ a0l){
    __shared__ float sE[4][SPECIES];
    int tid = threadIdx.x;
    int grp = tid >> 6;
    int f = tid & 63;
    int a = blockIdx.x * 4 + grp;
    const float* lg = logits + (long)a * SPECIES;
    float l0 = lg[f];
    float l1 = (f + 64 < SPECIES) ? lg[f + 64] : -1e30f;
    float mx = fmaxf(l0, l1);
    #pragma unroll
    for (int off = 32; off; off >>= 1) mx = fmaxf(mx, __shfl_xor(mx, off));
    float e0 = __expf(l0 - mx);
    float e1 = (f + 64 < SPECIES) ? __expf(l1 - mx) : 0.0f;
    sE[grp][f] = e0;
    if (f + 64 < SPECIES) sE[grp][64 + f] = e1;
    float sm = e0 + e1;
    #pragma unroll
    for (int off = 32; off; off >>= 1) sm += __shfl_xor(sm, off);
    __syncthreads();
    float acc = 0.0f;
    for (int s = 0; s < SPECIES; ++s) acc += sE[grp][s] * emb_w[s * FEA + f];
    float v = acc / sm + emb_b[f];
    atom0[(long)a * FEA + f] = v;
    u16 h, lo; split_bf16(v, h, lo);
    a0h[a * FEA + f] = h;
    a0l[a * FEA + f] = lo;
}

// ---------------- pairwise min-image distances + top-12 smallest ----------------
__global__ __launch_bounds__(256) void k_topk(const float* __restrict__ fracs,
        const float* __restrict__ lat, int* __restrict__ nbr_idx,
        float* __restrict__ nbr_dist){
    __shared__ float sD2[N_ATOMS];
    __shared__ float sWv[4];
    __shared__ int   sWi[4];
    int i = blockIdx.x, tid = threadIdx.x;
    float l00=lat[0],l01=lat[1],l02=lat[2];
    float l10=lat[3],l11=lat[4],l12=lat[5];
    float l20=lat[6],l21=lat[7],l22=lat[8];
    float fx = fracs[i*3+0], fy = fracs[i*3+1], fz = fracs[i*3+2];
    #pragma unroll
    for (int k = 0; k < 16; ++k){
        int j = tid + k * 256;
        float dx = fx - fracs[j*3+0];
        float dy = fy - fracs[j*3+1];
        float dz = fz - fracs[j*3+2];
        dx -= rintf(dx); dy -= rintf(dy); dz -= rintf(dz);
        float cx = dx*l00 + dy*l10 + dz*l20;
        float cy = dx*l01 + dy*l11 + dz*l21;
        float cz = dx*l02 + dy*l12 + dz*l22;
        float d2 = cx*cx + cy*cy + cz*cz;
        sD2[j] = (j == i) ? 3.4e38f : d2;
    }
    __syncthreads();
    for (int r = 0; r < M_NBR; ++r){
        float v = 3.4e38f; int id = N_ATOMS;
        #pragma unroll
        for (int k = 0; k < 16; ++k){
            int j = tid + k * 256;
            float x = sD2[j];
            if (x < v || (x == v && j < id)){ v = x; id = j; }
        }
        #pragma unroll
        for (int off = 32; off; off >>= 1){
            float ov = __shfl_down(v, off);
            int   oi = __shfl_down(id, off);
            if (ov < v || (ov == v && oi < id)){ v = ov; id = oi; }
        }
        if ((tid & 63) == 0){ sWv[tid >> 6] = v; sWi[tid >> 6] = id; }
        __syncthreads();
        if (tid == 0){
            float bv = sWv[0]; int bi = sWi[0];
            #pragma unroll
            for (int w = 1; w < 4; ++w){
                if (sWv[w] < bv || (sWv[w] == bv && sWi[w] < bi)){ bv = sWv[w]; bi = sWi[w]; }
            }
            nbr_idx[i * M_NBR + r]  = bi;
            nbr_dist[i * M_NBR + r] = sqrtf(bv);
            sD2[bi] = 3.4e38f;
        }
        __syncthreads();
    }
}

// ---------------- CGCNN conv layer via MFMA (bf16 hi/lo error compensation) ----------------
// 16 atoms/block (192 rows), 4 waves x 3 M-tiles x 8 N-tiles, K=192 in 6 chunks of 32.
// X row layout: [0:64)=self, [64:128)=nbr fea, [128:192)=gaussian.
__global__ __launch_bounds__(256, 2) void k_layer(
        const float* __restrict__ selfF,
        const u16* __restrict__ selfH, const u16* __restrict__ selfL,
        const u16* __restrict__ nbrH,  const u16* __restrict__ nbrL,
        const int* __restrict__ nbr_idx, const float* __restrict__ nbr_dist,
        const u16* __restrict__ wth, const u16* __restrict__ wtl,
        const float* __restrict__ bias, const float* __restrict__ gg,
        const float* __restrict__ bb,
        float* __restrict__ outF, u16* __restrict__ outH, u16* __restrict__ outL)
{
    __shared__ float prod[192][68];   // padded: row stride 272B (16B-aligned, bank-friendly)
    const int t = threadIdx.x;
    const int w = t >> 6, l = t & 63;
    const int lg = l >> 4, lr = l & 15;
    const int blk = blockIdx.x;
    const int rbase = blk * 192 + w * 48;

    int aidx[3], nidx[3];
    float dist[3];
    #pragma unroll
    for (int mt = 0; mt < 3; ++mt){
        int r = rbase + mt * 16 + lr;
        aidx[mt] = r / 12;
        nidx[mt] = nbr_idx[r];
        dist[mt] = nbr_dist[r];
    }
    float bv[8], gv[8], bev[8];
    #pragma unroll
    for (int nt = 0; nt < 8; ++nt){
        int c = nt * 16 + lr;
        bv[nt] = bias[c]; gv[nt] = gg[c]; bev[nt] = bb[c];
    }

    f32x4 acc[3][8];
    #pragma unroll
    for (int mt = 0; mt < 3; ++mt)
        #pragma unroll
        for (int nt = 0; nt < 8; ++nt) acc[mt][nt] = 0.0f;

    #pragma unroll
    for (int ch = 0; ch < 6; ++ch){
        bf16x8 ah[3], al[3];
        if (ch < 2){
            #pragma unroll
            for (int mt = 0; mt < 3; ++mt){
                int o = aidx[mt] * 64 + ch * 32 + lg * 8;
                ah[mt] = *(const bf16x8*)(selfH + o);
                al[mt] = *(const bf16x8*)(selfL + o);
            }
        } else if (ch < 4){
            #pragma unroll
            for (int mt = 0; mt < 3; ++mt){
                int o = nidx[mt] * 64 + (ch - 2) * 32 + lg * 8;
                ah[mt] = *(const bf16x8*)(nbrH + o);
                al[mt] = *(const bf16x8*)(nbrL + o);
            }
        } else {
            #pragma unroll
            for (int mt = 0; mt < 3; ++mt){
                float d = dist[mt];
                bf16x8 vh, vl;
                #pragma unroll
                for (int i = 0; i < 8; ++i){
                    int k = (ch - 4) * 32 + lg * 8 + i;
                    float off = (float)k * (8.0f / 63.0f);
                    float dd = d - off;
                    float v = __expf(GAUSS_COEFF * dd * dd);
                    u16 hh, ll; split_bf16(v, hh, ll);
                    vh[i] = (short)hh; vl[i] = (short)ll;
                }
                ah[mt] = vh; al[mt] = vl;
            }
        }
        #pragma unroll
        for (int nt = 0; nt < 8; ++nt){
            int wo = (nt * 16 + lr) * 192 + ch * 32 + lg * 8;
            bf16x8 bh = *(const bf16x8*)(wth + wo);
            bf16x8 bl = *(const bf16x8*)(wtl + wo);
            #pragma unroll
            for (int mt = 0; mt < 3; ++mt){
                acc[mt][nt] = __builtin_amdgcn_mfma_f32_16x16x32_bf16(al[mt], bh, acc[mt][nt], 0, 0, 0);
                acc[mt][nt] = __builtin_amdgcn_mfma_f32_16x16x32_bf16(ah[mt], bl, acc[mt][nt], 0, 0, 0);
                acc[mt][nt] = __builtin_amdgcn_mfma_f32_16x16x32_bf16(ah[mt], bh, acc[mt][nt], 0, 0, 0);
            }
        }
    }

    // LayerNorm (per row over 128 cols) + sigmoid*softplus, all in registers.
    // C layout: row_in_tile = lg*4 + r, col = nt*16 + lr  -> row lives in one 16-lane group.
    #pragma unroll
    for (int mt = 0; mt < 3; ++mt){
        float z[8][4];
        float s[4] = {0,0,0,0}, q[4] = {0,0,0,0};
        #pragma unroll
        for (int nt = 0; nt < 8; ++nt)
            #pragma unroll
            for (int r = 0; r < 4; ++r){
                float v = acc[mt][nt][r] + bv[nt];
                z[nt][r] = v;
                s[r] += v; q[r] += v * v;
            }
        #pragma unroll
        for (int r = 0; r < 4; ++r){
            #pragma unroll
            for (int m = 1; m < 16; m <<= 1){
                s[r] += __shfl_xor(s[r], m);
                q[r] += __shfl_xor(q[r], m);
            }
        }
        float mean[4], inv[4];
        #pragma unroll
        for (int r = 0; r < 4; ++r){
            mean[r] = s[r] * (1.0f / 128.0f);
            float var = q[r] * (1.0f / 128.0f) - mean[r] * mean[r];
            inv[r] = rsqrtf(var + LN_EPS);
        }
        #pragma unroll
        for (int nt = 0; nt < 4; ++nt)
            #pragma unroll
            for (int r = 0; r < 4; ++r){
                float zf = (z[nt][r]     - mean[r]) * inv[r] * gv[nt]     + bev[nt];
                float zc = (z[nt + 4][r] - mean[r]) * inv[r] * gv[nt + 4] + bev[nt + 4];
                float p = sigmoidf_(zf) * softplusf_(zc);
                prod[w * 48 + mt * 16 + lg * 4 + r][nt * 16 + lr] = p;
            }
    }
    __syncthreads();

    // per-atom reduction over 12 neighbor rows + residual + softplus
    {
        int a_loc = t >> 4;            // 0..15
        int c0 = (t & 15) * 4;         // 4 consecutive channels
        float4 sm = make_float4(0, 0, 0, 0);
        #pragma unroll
        for (int m = 0; m < 12; ++m){
            const float4 pv = *(const float4*)&prod[a_loc * 12 + m][c0];
            sm.x += pv.x; sm.y += pv.y; sm.z += pv.z; sm.w += pv.w;
        }
        int atom = blk * 16 + a_loc;
        const float4 sf = *(const float4*)(selfF + (long)atom * 64 + c0);
        float o[4];
        o[0] = softplusf_(sf.x + sm.x);
        o[1] = softplusf_(sf.y + sm.y);
        o[2] = softplusf_(sf.z + sm.z);
        o[3] = softplusf_(sf.w + sm.w);
        *(float4*)(outF + (long)atom * 64 + c0) = make_float4(o[0], o[1], o[2], o[3]);
        u16 h0,l0,h1,l1,h2,l2,h3,l3;
        split_bf16(o[0], h0, l0); split_bf16(o[1], h1, l1);
        split_bf16(o[2], h2, l2); split_bf16(o[3], h3, l3);
        ushort4 hv; hv.x=h0; hv.y=h1; hv.z=h2; hv.w=h3;
        ushort4 lv; lv.x=l0; lv.y=l1; lv.z=l2; lv.w=l3;
        *(ushort4*)(outH + atom * 64 + c0) = hv;
        *(ushort4*)(outL + atom * 64 + c0) = lv;
    }
}

// ---------------- pooling: deterministic two-stage tree ----------------
__global__ __launch_bounds__(256) void k_partial(const float* __restrict__ atom,
        const float* __restrict__ occ, float* __restrict__ partials){
    int b = blockIdx.x, tid = threadIdx.x;
    int f = tid & 63, sub = tid >> 6;
    __shared__ float sAcc[256];
    float acc = 0.0f;
    for (int it = 0; it < 16; ++it){
        int a = b * 64 + sub + it * 4;
        float p = sigmoidf_(occ[a]);
        acc += atom[(long)a * FEA + f] * p;
    }
    sAcc[tid] = acc;
    __syncthreads();
    if (tid < 64){
        float s = sAcc[f] + sAcc[64 + f] + sAcc[128 + f] + sAcc[192 + f];
        partials[b * 65 + f] = s;
        float po = sigmoidf_(occ[b * 64 + f]);
        #pragma unroll
        for (int off = 32; off; off >>= 1) po += __shfl_down(po, off);
        if (f == 0) partials[b * 65 + 64] = po;
    }
}

__global__ __launch_bounds__(64) void k_final(const float* __restrict__ partials,
        const float* __restrict__ fc_w, const float* __restrict__ fc_b,
        float* __restrict__ out){
    int f = threadIdx.x;
    float num = 0.0f;
    for (int p = 0; p < 64; ++p) num += partials[p * 65 + f];
    float occs = partials[f * 65 + 64];
    #pragma unroll
    for (int off = 32; off; off >>= 1) occs += __shfl_down(occs, off);
    occs = __shfl(occs, 0);
    float gf = num / (occs + 1e-6f);
    float v = gf * fc_w[f];
    #pragma unroll
    for (int off = 32; off; off >>= 1) v += __shfl_down(v, off);
    if (f == 0) out[0] = v + fc_b[0];
}

extern "C" void kernel_launch(void* const* d_in, const int* in_sizes, int n_in,
                              void* d_out, int out_size, void* d_ws, size_t ws_size,
                              hipStream_t stream) {
    const float* lat    = (const float*)d_in[0];
    const float* fracs  = (const float*)d_in[1];
    const float* slog   = (const float*)d_in[2];
    const float* occ    = (const float*)d_in[3];
    const float* emb_w  = (const float*)d_in[4];
    const float* emb_b  = (const float*)d_in[5];
    const float* w1     = (const float*)d_in[6];
    const float* b1     = (const float*)d_in[7];
    const float* g1     = (const float*)d_in[8];
    const float* be1    = (const float*)d_in[9];
    const float* w2     = (const float*)d_in[10];
    const float* b2     = (const float*)d_in[11];
    const float* g2     = (const float*)d_in[12];
    const float* be2    = (const float*)d_in[13];
    const float* fc_w   = (const float*)d_in[14];
    const float* fc_b   = (const float*)d_in[15];
    float* out = (float*)d_out;

    char* ws = (char*)d_ws;
    auto alloc = [&](size_t bytes) -> void* {
        void* p = (void*)ws;
        ws += (bytes + 255) & ~(size_t)255;
        return p;
    };
    int*   nbr_idx  = (int*)  alloc((size_t)N_ATOMS * M_NBR * 4);
    float* nbr_dist = (float*)alloc((size_t)N_ATOMS * M_NBR * 4);
    float* atom0    = (float*)alloc((size_t)N_ATOMS * FEA * 4);
    float* atom1    = (float*)alloc((size_t)N_ATOMS * FEA * 4);
    u16*   a0h      = (u16*)  alloc((size_t)N_ATOMS * FEA * 2);
    u16*   a0l      = (u16*)  alloc((size_t)N_ATOMS * FEA * 2);
    u16*   a1h      = (u16*)  alloc((size_t)N_ATOMS * FEA * 2);
    u16*   a1l      = (u16*)  alloc((size_t)N_ATOMS * FEA * 2);
    u16*   wt1h     = (u16*)  alloc((size_t)192 * 128 * 2);
    u16*   wt1l     = (u16*)  alloc((size_t)192 * 128 * 2);
    u16*   wt2h     = (u16*)  alloc((size_t)192 * 128 * 2);
    u16*   wt2l     = (u16*)  alloc((size_t)192 * 128 * 2);
    float* partials = (float*)alloc((size_t)64 * 65 * 4);

    k_prepw  <<<192, 256, 0, stream>>>(w1, w2, wt1h, wt1l, wt2h, wt2l);
    k_embed  <<<N_ATOMS / 4, 256, 0, stream>>>(slog, emb_w, emb_b, atom0, a0h, a0l);
    k_topk   <<<N_ATOMS, 256, 0, stream>>>(fracs, lat, nbr_idx, nbr_dist);
    k_layer  <<<N_ATOMS / 16, 256, 0, stream>>>(atom0, a0h, a0l, a0h, a0l,
                nbr_idx, nbr_dist, wt1h, wt1l, b1, g1, be1, atom1, a1h, a1l);
    k_layer  <<<N_ATOMS / 16, 256, 0, stream>>>(atom1, a1h, a1l, a0h, a0l,
                nbr_idx, nbr_dist, wt2h, wt2l, b2, g2, be2, atom1, a1h, a1l);
    k_partial<<<64, 256, 0, stream>>>(atom1, occ, partials);
    k_final  <<<1, 64, 0, stream>>>(partials, fc_w, fc_b, out);
}